// Round 1
// baseline (1328.719 us; speedup 1.0000x reference)
//
#include <hip/hip_runtime.h>
#include <math.h>

// ---------------------------------------------------------------------------
// GCN: 4x (GEMM -> symmetric-normalized aggregation (+bias, leaky_relu)) -> softmax
// Graph prep per call: degree count -> rsqrt -> prefix-sum -> CSR scatter.
// ---------------------------------------------------------------------------

__global__ void deg_count_kernel(const int* __restrict__ dst, int* __restrict__ degi, int E) {
    int e = blockIdx.x * blockDim.x + threadIdx.x;
    if (e < E) atomicAdd(&degi[dst[e]], 1);
}

__global__ void dis_kernel(const int* __restrict__ degi, float* __restrict__ dis, int n) {
    int i = blockIdx.x * blockDim.x + threadIdx.x;
    if (i < n) dis[i] = rsqrtf((float)(degi[i] + 1));  // +1 self-loop; always >= 1
}

// Single-block exclusive prefix sum over degi[0..n) -> row_start[0..n]
__global__ void scan_kernel(const int* __restrict__ degi, int* __restrict__ row_start, int n) {
    __shared__ int buf[1024];
    __shared__ int carry;
    if (threadIdx.x == 0) carry = 0;
    __syncthreads();
    for (int base = 0; base < n; base += 1024) {
        int i = base + (int)threadIdx.x;
        int v = (i < n) ? degi[i] : 0;
        buf[threadIdx.x] = v;
        __syncthreads();
        #pragma unroll
        for (int off = 1; off < 1024; off <<= 1) {
            int t = (threadIdx.x >= (unsigned)off) ? buf[threadIdx.x - off] : 0;
            __syncthreads();
            buf[threadIdx.x] += t;
            __syncthreads();
        }
        if (i < n) row_start[i] = carry + buf[threadIdx.x] - v;  // exclusive
        __syncthreads();
        if (threadIdx.x == 0) carry += buf[1023];
        __syncthreads();
    }
    if (threadIdx.x == 0) row_start[n] = carry;
}

__global__ void scatter_kernel(const int* __restrict__ srcArr, const int* __restrict__ dstArr,
                               const float* __restrict__ dis, const int* __restrict__ row_start,
                               int* __restrict__ cursor, int* __restrict__ csr_src,
                               float* __restrict__ csr_norm, int E) {
    int e = blockIdx.x * blockDim.x + threadIdx.x;
    if (e >= E) return;
    int s = srcArr[e], d = dstArr[e];
    int p = atomicAdd(&cursor[d], 1);
    int idx = row_start[d] + p;
    csr_src[idx]  = s;
    csr_norm[idx] = dis[s] * dis[d];
}

// C[M x Nout] = A[M x K] @ W[K x Nout], fp32, 64x64 tile, BK=32, 256 thr, 4x4 microtile
__global__ __launch_bounds__(256) void sgemm64(const float* __restrict__ A,
                                               const float* __restrict__ W,
                                               float* __restrict__ C,
                                               int M, int K, int Nout) {
    const int BM = 64, BN = 64, BK = 32;
    __shared__ float As[BK][BM + 1];  // [k][m], +1 pad: conflict-free stores
    __shared__ float Ws[BK][BN];      // [k][n]
    int m0 = blockIdx.x * BM, n0 = blockIdx.y * BN;
    int t  = threadIdx.x;
    int tx = t & 15, ty = t >> 4;
    float acc[4][4] = {};
    for (int k0 = 0; k0 < K; k0 += BK) {
        #pragma unroll
        for (int i = 0; i < 8; ++i) {            // 64x32 A tile
            int idx = i * 256 + t;
            int m = idx >> 5, k = idx & 31;
            int gm = m0 + m, gk = k0 + k;
            float v = 0.f;
            if (gm < M && gk < K) v = A[(size_t)gm * K + gk];
            As[k][m] = v;
        }
        #pragma unroll
        for (int i = 0; i < 8; ++i) {            // 32x64 W tile
            int idx = i * 256 + t;
            int k = idx >> 6, n = idx & 63;
            int gk = k0 + k, gn = n0 + n;
            float v = 0.f;
            if (gk < K && gn < Nout) v = W[(size_t)gk * Nout + gn];
            Ws[k][n] = v;
        }
        __syncthreads();
        #pragma unroll
        for (int kk = 0; kk < BK; ++kk) {
            float a[4], w[4];
            #pragma unroll
            for (int i = 0; i < 4; ++i) a[i] = As[kk][ty * 4 + i];
            #pragma unroll
            for (int j = 0; j < 4; ++j) w[j] = Ws[kk][tx * 4 + j];
            #pragma unroll
            for (int i = 0; i < 4; ++i)
                #pragma unroll
                for (int j = 0; j < 4; ++j) acc[i][j] += a[i] * w[j];
        }
        __syncthreads();
    }
    #pragma unroll
    for (int i = 0; i < 4; ++i) {
        int gm = m0 + ty * 4 + i;
        if (gm >= M) continue;
        #pragma unroll
        for (int j = 0; j < 4; ++j) {
            int gn = n0 + tx * 4 + j;
            if (gn < Nout) C[(size_t)gm * Nout + gn] = acc[i][j];
        }
    }
}

// One wave per node; lane = feature (R regs of 64). Self-loop folded in.
template <int F, bool RELU>
__global__ void aggregate_kernel(const float* __restrict__ h, const int* __restrict__ row_start,
                                 const int* __restrict__ csr_src, const float* __restrict__ csr_norm,
                                 const float* __restrict__ dis, const float* __restrict__ bias,
                                 float* __restrict__ out, int n) {
    constexpr int R = (F + 63) / 64;
    int wid  = threadIdx.x >> 6;
    int lane = threadIdx.x & 63;
    int node = blockIdx.x * (blockDim.x >> 6) + wid;
    if (node >= n) return;
    float dn = dis[node];
    float acc[R];
    #pragma unroll
    for (int r = 0; r < R; ++r) {
        int f = lane + 64 * r;
        acc[r] = (f < F) ? h[(size_t)node * F + f] * (dn * dn) : 0.f;
    }
    int beg = row_start[node], end = row_start[node + 1];
    for (int i = beg; i < end; ++i) {
        int s = csr_src[i];
        float nrm = csr_norm[i];
        #pragma unroll
        for (int r = 0; r < R; ++r) {
            int f = lane + 64 * r;
            if (f < F) acc[r] += h[(size_t)s * F + f] * nrm;
        }
    }
    #pragma unroll
    for (int r = 0; r < R; ++r) {
        int f = lane + 64 * r;
        if (f < F) {
            float v = acc[r] + bias[f];
            if (RELU) v = (v > 0.f) ? v : 0.1f * v;
            out[(size_t)node * F + f] = v;
        }
    }
}

// Final layer: F=2, aggregation + bias + softmax. One thread per node.
__global__ void aggregate2_softmax_kernel(const float* __restrict__ h, const int* __restrict__ row_start,
                                          const int* __restrict__ csr_src, const float* __restrict__ csr_norm,
                                          const float* __restrict__ dis, const float* __restrict__ bias,
                                          float* __restrict__ out, int n) {
    int node = blockIdx.x * blockDim.x + threadIdx.x;
    if (node >= n) return;
    float dn = dis[node];
    float a0 = h[2 * (size_t)node]     * (dn * dn);
    float a1 = h[2 * (size_t)node + 1] * (dn * dn);
    int beg = row_start[node], end = row_start[node + 1];
    for (int i = beg; i < end; ++i) {
        int s = csr_src[i];
        float nrm = csr_norm[i];
        a0 += h[2 * (size_t)s]     * nrm;
        a1 += h[2 * (size_t)s + 1] * nrm;
    }
    a0 += bias[0];
    a1 += bias[1];
    float m  = fmaxf(a0, a1);
    float e0 = expf(a0 - m), e1 = expf(a1 - m);
    float inv = 1.f / (e0 + e1);
    out[2 * (size_t)node]     = e0 * inv;
    out[2 * (size_t)node + 1] = e1 * inv;
}

extern "C" void kernel_launch(void* const* d_in, const int* in_sizes, int n_in,
                              void* d_out, int out_size, void* d_ws, size_t ws_size,
                              hipStream_t stream) {
    const float* x  = (const float*)d_in[0];
    const int*   ei = (const int*)d_in[1];
    const float* W1 = (const float*)d_in[2];
    const float* b1 = (const float*)d_in[3];
    const float* W2 = (const float*)d_in[4];
    const float* b2 = (const float*)d_in[5];
    const float* W3 = (const float*)d_in[6];
    const float* b3 = (const float*)d_in[7];
    const float* W4 = (const float*)d_in[8];
    const float* b4 = (const float*)d_in[9];

    const int N = in_sizes[0] / 256;
    const int E = in_sizes[1] / 2;
    const int* srcA = ei;
    const int* dstA = ei + E;

    // workspace carve-up
    char* ws = (char*)d_ws;
    size_t off = 0;
    auto alloc = [&](size_t bytes) {
        void* p = ws + off;
        off = (off + bytes + 255) & ~(size_t)255;
        return p;
    };
    int*   degi      = (int*)alloc((size_t)N * 4);
    float* dis       = (float*)alloc((size_t)N * 4);
    int*   row_start = (int*)alloc((size_t)(N + 1) * 4);
    int*   cursor    = (int*)alloc((size_t)N * 4);
    int*   csr_src   = (int*)alloc((size_t)E * 4);
    float* csr_norm  = (float*)alloc((size_t)E * 4);
    float* bufA      = (float*)alloc((size_t)N * 128 * 4);
    float* bufB      = (float*)alloc((size_t)N * 128 * 4);
    (void)ws_size;

    hipMemsetAsync(degi,   0, (size_t)N * 4, stream);
    hipMemsetAsync(cursor, 0, (size_t)N * 4, stream);

    deg_count_kernel<<<(E + 255) / 256, 256, 0, stream>>>(dstA, degi, E);
    dis_kernel<<<(N + 255) / 256, 256, 0, stream>>>(degi, dis, N);
    scan_kernel<<<1, 1024, 0, stream>>>(degi, row_start, N);
    scatter_kernel<<<(E + 255) / 256, 256, 0, stream>>>(srcA, dstA, dis, row_start,
                                                        cursor, csr_src, csr_norm, E);

    const int nodeBlocks = (N + 3) / 4;  // 4 waves/block, 1 node/wave

    // layer 1: 256 -> 128
    {
        dim3 g((N + 63) / 64, (128 + 63) / 64);
        sgemm64<<<g, 256, 0, stream>>>(x, W1, bufA, N, 256, 128);
        aggregate_kernel<128, true><<<nodeBlocks, 256, 0, stream>>>(
            bufA, row_start, csr_src, csr_norm, dis, b1, bufB, N);
    }
    // layer 2: 128 -> 100
    {
        dim3 g((N + 63) / 64, (100 + 63) / 64);
        sgemm64<<<g, 256, 0, stream>>>(bufB, W2, bufA, N, 128, 100);
        aggregate_kernel<100, true><<<nodeBlocks, 256, 0, stream>>>(
            bufA, row_start, csr_src, csr_norm, dis, b2, bufB, N);
    }
    // layer 3: 100 -> 32
    {
        dim3 g((N + 63) / 64, 1);
        sgemm64<<<g, 256, 0, stream>>>(bufB, W3, bufA, N, 100, 32);
        aggregate_kernel<32, true><<<nodeBlocks, 256, 0, stream>>>(
            bufA, row_start, csr_src, csr_norm, dis, b3, bufB, N);
    }
    // layer 4: 32 -> 2, then softmax
    {
        dim3 g((N + 63) / 64, 1);
        sgemm64<<<g, 256, 0, stream>>>(bufB, W4, bufA, N, 32, 2);
        aggregate2_softmax_kernel<<<(N + 255) / 256, 256, 0, stream>>>(
            bufA, row_start, csr_src, csr_norm, dis, b4, (float*)d_out, N);
    }
}

// Round 2
// 442.047 us; speedup vs baseline: 3.0058x; 3.0058x over previous
//
#include <hip/hip_runtime.h>
#include <math.h>

// ---------------------------------------------------------------------------
// GCN: 4x (bf16-MFMA GEMM -> symmetric-normalized aggregation (+bias, lrelu))
//      -> softmax.  Graph prep per call: degree -> rsqrt -> scan -> CSR.
// All intermediate feature buffers are bf16 (halves gather traffic, feeds MFMA).
// ---------------------------------------------------------------------------

typedef unsigned short ushort_t;
typedef unsigned int   uint_t;
typedef short  bf16x8 __attribute__((ext_vector_type(8)));
typedef float  f32x4  __attribute__((ext_vector_type(4)));

__device__ __forceinline__ ushort_t f2bf(float f) {
    union { float f; uint_t u; } v; v.f = f;
    uint_t u = v.u;
    u += 0x7fffu + ((u >> 16) & 1u);      // round-to-nearest-even
    return (ushort_t)(u >> 16);
}
__device__ __forceinline__ float bflo(uint_t u) {
    union { uint_t q; float f; } v; v.q = u << 16; return v.f;
}
__device__ __forceinline__ float bfhi(uint_t u) {
    union { uint_t q; float f; } v; v.q = u & 0xffff0000u; return v.f;
}

// ------------------------------- graph prep -------------------------------

__global__ void deg_count_kernel(const int* __restrict__ dst, int* __restrict__ degi, int E) {
    int e = blockIdx.x * blockDim.x + threadIdx.x;
    if (e < E) atomicAdd(&degi[dst[e]], 1);
}

__global__ void dis_kernel(const int* __restrict__ degi, float* __restrict__ dis, int n) {
    int i = blockIdx.x * blockDim.x + threadIdx.x;
    if (i < n) dis[i] = rsqrtf((float)(degi[i] + 1));  // +1 self-loop
}

// hierarchical exclusive scan: per-1024-block scan + block sums
__global__ void scan_block_kernel(const int* __restrict__ degi, int* __restrict__ row_excl,
                                  int* __restrict__ bsums, int n) {
    __shared__ int buf[1024];
    int i = blockIdx.x * 1024 + threadIdx.x;
    int v = (i < n) ? degi[i] : 0;
    buf[threadIdx.x] = v;
    __syncthreads();
    for (int off = 1; off < 1024; off <<= 1) {
        int t = (threadIdx.x >= (unsigned)off) ? buf[threadIdx.x - off] : 0;
        __syncthreads();
        buf[threadIdx.x] += t;
        __syncthreads();
    }
    if (i < n) row_excl[i] = buf[threadIdx.x] - v;
    if (threadIdx.x == 1023) bsums[blockIdx.x] = buf[1023];
}

// single block, nb <= 128: exclusive scan of bsums in place, total at bsums[nb]
__global__ void scan_sums_kernel(int* __restrict__ bsums, int nb) {
    __shared__ int buf[128];
    int v = ((int)threadIdx.x < nb) ? bsums[threadIdx.x] : 0;
    buf[threadIdx.x] = v;
    __syncthreads();
    for (int off = 1; off < 128; off <<= 1) {
        int t = (threadIdx.x >= (unsigned)off) ? buf[threadIdx.x - off] : 0;
        __syncthreads();
        buf[threadIdx.x] += t;
        __syncthreads();
    }
    if ((int)threadIdx.x < nb) bsums[threadIdx.x] = buf[threadIdx.x] - v;
    if (threadIdx.x == 0) bsums[nb] = buf[127];
}

__global__ void scan_add_kernel(int* __restrict__ row_start, const int* __restrict__ bsums,
                                int n, int nb) {
    int i = blockIdx.x * blockDim.x + threadIdx.x;
    if (i < n) row_start[i] += bsums[i >> 10];
    else if (i == n) row_start[n] = bsums[nb];
}

__global__ void scatter_kernel(const int* __restrict__ srcArr, const int* __restrict__ dstArr,
                               const float* __restrict__ dis, const int* __restrict__ row_start,
                               int* __restrict__ cursor, int* __restrict__ csr_src,
                               float* __restrict__ csr_norm, int E) {
    int e = blockIdx.x * blockDim.x + threadIdx.x;
    if (e >= E) return;
    int s = srcArr[e], d = dstArr[e];
    int p = atomicAdd(&cursor[d], 1);
    int idx = row_start[d] + p;
    csr_src[idx]  = s;
    csr_norm[idx] = dis[s] * dis[d];
}

// ------------------------------ dtype converts ----------------------------

// fp32 -> bf16, n divisible by 4
__global__ void cast_bf16_kernel(const float* __restrict__ in, ushort_t* __restrict__ out, size_t n4) {
    size_t i = (size_t)blockIdx.x * blockDim.x + threadIdx.x;
    if (i >= n4) return;
    const float4 v = ((const float4*)in)[i];
    ushort_t o[4] = { f2bf(v.x), f2bf(v.y), f2bf(v.z), f2bf(v.w) };
    ((uint2*)out)[i] = *(const uint2*)o;
}

// W [K x N] fp32 -> Wt [NP x KP] bf16 (transposed + zero-padded)
__global__ void wt_kernel(const float* __restrict__ W, ushort_t* __restrict__ Wt,
                          int K, int N, int KP, int NP) {
    int idx = blockIdx.x * blockDim.x + threadIdx.x;
    if (idx >= KP * NP) return;
    int n = idx / KP, k = idx % KP;
    float v = (k < K && n < N) ? W[(size_t)k * N + n] : 0.f;
    Wt[(size_t)n * KP + k] = f2bf(v);
}

// ------------------------------ MFMA GEMM ---------------------------------
// C[M x nstore] (bf16, stride ldc) = A[M x K] (bf16, stride lda)
//                                  @ Bt[NP x K]^T (bf16, stride ldb, N-major)
// BM=128 BN=64 BK=64, 4 waves (2Mx2N), per-wave 64x32 out (4x2 frags).
__global__ __launch_bounds__(256) void mfma_gemm(const ushort_t* __restrict__ A,
                                                 const ushort_t* __restrict__ Bt,
                                                 ushort_t* __restrict__ C,
                                                 int M, int K, int lda, int ldb,
                                                 int ldc, int nstore) {
    __shared__ __attribute__((aligned(16))) ushort_t As[128][72];  // +8 pad: banks spread
    __shared__ __attribute__((aligned(16))) ushort_t Bs[64][72];

    const int t    = threadIdx.x;
    const int lane = t & 63;
    const int w    = t >> 6;
    const int wm   = w >> 1, wn = w & 1;
    const int m0   = blockIdx.x * 128;
    const int n0   = blockIdx.y * 64;

    f32x4 acc[4][2];
    #pragma unroll
    for (int mi = 0; mi < 4; ++mi)
        #pragma unroll
        for (int ni = 0; ni < 2; ++ni) acc[mi][ni] = (f32x4){0.f, 0.f, 0.f, 0.f};

    const int srow = t >> 3;          // 0..31
    const int scol = (t & 7) * 8;     // 0..56

    for (int k0 = 0; k0 < K; k0 += 64) {
        #pragma unroll
        for (int it = 0; it < 4; ++it) {            // A tile 128x64
            int r = srow + it * 32;
            int gm = m0 + r;
            bf16x8 v = {0, 0, 0, 0, 0, 0, 0, 0};
            if (gm < M) v = *(const bf16x8*)(A + (size_t)gm * lda + k0 + scol);
            *(bf16x8*)&As[r][scol] = v;
        }
        #pragma unroll
        for (int it = 0; it < 2; ++it) {            // B tile 64x64 (rows padded)
            int r = srow + it * 32;
            bf16x8 v = *(const bf16x8*)(Bt + (size_t)(n0 + r) * ldb + k0 + scol);
            *(bf16x8*)&Bs[r][scol] = v;
        }
        __syncthreads();
        #pragma unroll
        for (int kk = 0; kk < 2; ++kk) {
            bf16x8 af[4], bfr[2];
            const int kc = kk * 32 + (lane >> 4) * 8;
            #pragma unroll
            for (int mi = 0; mi < 4; ++mi)
                af[mi] = *(const bf16x8*)&As[wm * 64 + mi * 16 + (lane & 15)][kc];
            #pragma unroll
            for (int ni = 0; ni < 2; ++ni)
                bfr[ni] = *(const bf16x8*)&Bs[wn * 32 + ni * 16 + (lane & 15)][kc];
            #pragma unroll
            for (int mi = 0; mi < 4; ++mi)
                #pragma unroll
                for (int ni = 0; ni < 2; ++ni)
                    acc[mi][ni] = __builtin_amdgcn_mfma_f32_16x16x32_bf16(
                        af[mi], bfr[ni], acc[mi][ni], 0, 0, 0);
        }
        __syncthreads();
    }

    // C/D layout: col = lane&15, row = (lane>>4)*4 + r   [m89-verified]
    #pragma unroll
    for (int mi = 0; mi < 4; ++mi)
        #pragma unroll
        for (int ni = 0; ni < 2; ++ni)
            #pragma unroll
            for (int r = 0; r < 4; ++r) {
                int gm = m0 + wm * 64 + mi * 16 + (lane >> 4) * 4 + r;
                int gn = n0 + wn * 32 + ni * 16 + (lane & 15);
                if (gm < M && gn < nstore)
                    C[(size_t)gm * ldc + gn] = f2bf(acc[mi][ni][r]);
            }
}

// ---------------------------- aggregation ---------------------------------
// FPAD=128: one wave per node, lane holds features {2l, 2l+1} (uint = 2 bf16).
template <int F>
__global__ void aggregate128_kernel(const ushort_t* __restrict__ h, const int* __restrict__ row_start,
                                    const int* __restrict__ csr_src, const float* __restrict__ csr_norm,
                                    const float* __restrict__ dis, const float* __restrict__ bias,
                                    ushort_t* __restrict__ out, int n) {
    int wid  = threadIdx.x >> 6;
    int lane = threadIdx.x & 63;
    int node = blockIdx.x * (blockDim.x >> 6) + wid;
    if (node >= n) return;
    const int f0 = 2 * lane, f1 = f0 + 1;
    float dn = dis[node];
    uint_t v = *(const uint_t*)(h + (size_t)node * 128 + f0);
    float acc0 = bflo(v) * (dn * dn);
    float acc1 = bfhi(v) * (dn * dn);
    int i = row_start[node], end = row_start[node + 1];
    for (; i + 4 <= end; i += 4) {
        int s0 = csr_src[i], s1 = csr_src[i + 1], s2 = csr_src[i + 2], s3 = csr_src[i + 3];
        float m0 = csr_norm[i], m1 = csr_norm[i + 1], m2 = csr_norm[i + 2], m3 = csr_norm[i + 3];
        uint_t u0 = *(const uint_t*)(h + (size_t)s0 * 128 + f0);
        uint_t u1 = *(const uint_t*)(h + (size_t)s1 * 128 + f0);
        uint_t u2 = *(const uint_t*)(h + (size_t)s2 * 128 + f0);
        uint_t u3 = *(const uint_t*)(h + (size_t)s3 * 128 + f0);
        acc0 += bflo(u0) * m0; acc1 += bfhi(u0) * m0;
        acc0 += bflo(u1) * m1; acc1 += bfhi(u1) * m1;
        acc0 += bflo(u2) * m2; acc1 += bfhi(u2) * m2;
        acc0 += bflo(u3) * m3; acc1 += bfhi(u3) * m3;
    }
    for (; i < end; ++i) {
        int s = csr_src[i];
        float nrm = csr_norm[i];
        uint_t u = *(const uint_t*)(h + (size_t)s * 128 + f0);
        acc0 += bflo(u) * nrm; acc1 += bfhi(u) * nrm;
    }
    acc0 += (f0 < F) ? bias[f0] : 0.f;
    acc1 += (f1 < F) ? bias[f1] : 0.f;
    acc0 = (acc0 > 0.f) ? acc0 : 0.1f * acc0;
    acc1 = (acc1 > 0.f) ? acc1 : 0.1f * acc1;
    if (f0 >= F) acc0 = 0.f;   // keep K-padding exactly zero
    if (f1 >= F) acc1 = 0.f;
    uint_t o = (uint_t)f2bf(acc0) | ((uint_t)f2bf(acc1) << 16);
    *(uint_t*)(out + (size_t)node * 128 + f0) = o;
}

// F=32: 16-lane group per node (2 features per lane), 4 nodes per wave.
__global__ void aggregate32_kernel(const ushort_t* __restrict__ h, const int* __restrict__ row_start,
                                   const int* __restrict__ csr_src, const float* __restrict__ csr_norm,
                                   const float* __restrict__ dis, const float* __restrict__ bias,
                                   ushort_t* __restrict__ out, int n) {
    int lane16 = threadIdx.x & 15;
    int node = blockIdx.x * (blockDim.x >> 4) + (threadIdx.x >> 4);
    if (node >= n) return;
    const int f0 = 2 * lane16;
    float dn = dis[node];
    uint_t v = *(const uint_t*)(h + (size_t)node * 32 + f0);
    float acc0 = bflo(v) * (dn * dn);
    float acc1 = bfhi(v) * (dn * dn);
    int i = row_start[node], end = row_start[node + 1];
    for (; i + 4 <= end; i += 4) {
        int s0 = csr_src[i], s1 = csr_src[i + 1], s2 = csr_src[i + 2], s3 = csr_src[i + 3];
        float m0 = csr_norm[i], m1 = csr_norm[i + 1], m2 = csr_norm[i + 2], m3 = csr_norm[i + 3];
        uint_t u0 = *(const uint_t*)(h + (size_t)s0 * 32 + f0);
        uint_t u1 = *(const uint_t*)(h + (size_t)s1 * 32 + f0);
        uint_t u2 = *(const uint_t*)(h + (size_t)s2 * 32 + f0);
        uint_t u3 = *(const uint_t*)(h + (size_t)s3 * 32 + f0);
        acc0 += bflo(u0) * m0; acc1 += bfhi(u0) * m0;
        acc0 += bflo(u1) * m1; acc1 += bfhi(u1) * m1;
        acc0 += bflo(u2) * m2; acc1 += bfhi(u2) * m2;
        acc0 += bflo(u3) * m3; acc1 += bfhi(u3) * m3;
    }
    for (; i < end; ++i) {
        int s = csr_src[i];
        float nrm = csr_norm[i];
        uint_t u = *(const uint_t*)(h + (size_t)s * 32 + f0);
        acc0 += bflo(u) * nrm; acc1 += bfhi(u) * nrm;
    }
    acc0 += bias[f0];
    acc1 += bias[f0 + 1];
    acc0 = (acc0 > 0.f) ? acc0 : 0.1f * acc0;
    acc1 = (acc1 > 0.f) ? acc1 : 0.1f * acc1;
    uint_t o = (uint_t)f2bf(acc0) | ((uint_t)f2bf(acc1) << 16);
    *(uint_t*)(out + (size_t)node * 32 + f0) = o;
}

// layer 4 GEMM: [N x 32] bf16 @ [32 x 2] fp32 -> fp32, one thread per node
__global__ void gemm32x2_kernel(const ushort_t* __restrict__ H, const float* __restrict__ W4,
                                float* __restrict__ C, int n) {
    int node = blockIdx.x * blockDim.x + threadIdx.x;
    if (node >= n) return;
    const uint_t* row = (const uint_t*)(H + (size_t)node * 32);
    float a0 = 0.f, a1 = 0.f;
    #pragma unroll
    for (int k2 = 0; k2 < 16; ++k2) {
        uint_t u = row[k2];
        float x0 = bflo(u), x1 = bfhi(u);
        int k = 2 * k2;
        a0 += x0 * W4[k * 2]     + x1 * W4[(k + 1) * 2];
        a1 += x0 * W4[k * 2 + 1] + x1 * W4[(k + 1) * 2 + 1];
    }
    C[2 * (size_t)node] = a0;
    C[2 * (size_t)node + 1] = a1;
}

// final aggregation (F=2) + bias + softmax, one thread per node
__global__ void aggregate2_softmax_kernel(const float* __restrict__ h, const int* __restrict__ row_start,
                                          const int* __restrict__ csr_src, const float* __restrict__ csr_norm,
                                          const float* __restrict__ dis, const float* __restrict__ bias,
                                          float* __restrict__ out, int n) {
    int node = blockIdx.x * blockDim.x + threadIdx.x;
    if (node >= n) return;
    float dn = dis[node];
    float a0 = h[2 * (size_t)node]     * (dn * dn);
    float a1 = h[2 * (size_t)node + 1] * (dn * dn);
    int beg = row_start[node], end = row_start[node + 1];
    for (int i = beg; i < end; ++i) {
        int s = csr_src[i];
        float nrm = csr_norm[i];
        a0 += h[2 * (size_t)s]     * nrm;
        a1 += h[2 * (size_t)s + 1] * nrm;
    }
    a0 += bias[0];
    a1 += bias[1];
    float m  = fmaxf(a0, a1);
    float e0 = expf(a0 - m), e1 = expf(a1 - m);
    float inv = 1.f / (e0 + e1);
    out[2 * (size_t)node]     = e0 * inv;
    out[2 * (size_t)node + 1] = e1 * inv;
}

// ---------------------------------------------------------------------------

extern "C" void kernel_launch(void* const* d_in, const int* in_sizes, int n_in,
                              void* d_out, int out_size, void* d_ws, size_t ws_size,
                              hipStream_t stream) {
    const float* x  = (const float*)d_in[0];
    const int*   ei = (const int*)d_in[1];
    const float* W1 = (const float*)d_in[2];
    const float* b1 = (const float*)d_in[3];
    const float* W2 = (const float*)d_in[4];
    const float* b2 = (const float*)d_in[5];
    const float* W3 = (const float*)d_in[6];
    const float* b3 = (const float*)d_in[7];
    const float* W4 = (const float*)d_in[8];
    const float* b4 = (const float*)d_in[9];

    const int N = in_sizes[0] / 256;
    const int E = in_sizes[1] / 2;
    const int* srcA = ei;
    const int* dstA = ei + E;

    char* ws = (char*)d_ws;
    size_t off = 0;
    auto alloc = [&](size_t bytes) {
        void* p = ws + off;
        off = (off + bytes + 255) & ~(size_t)255;
        return p;
    };
    int*      degi      = (int*)alloc((size_t)N * 4);
    float*    dis       = (float*)alloc((size_t)N * 4);
    int*      row_start = (int*)alloc((size_t)(N + 1) * 4);
    int*      cursor    = (int*)alloc((size_t)N * 4);
    int*      bsums     = (int*)alloc(512 * 4);
    int*      csr_src   = (int*)alloc((size_t)E * 4);
    float*    csr_norm  = (float*)alloc((size_t)E * 4);
    ushort_t* xb        = (ushort_t*)alloc((size_t)N * 256 * 2);
    ushort_t* bufA      = (ushort_t*)alloc((size_t)N * 128 * 2);
    ushort_t* bufB      = (ushort_t*)alloc((size_t)N * 128 * 2);
    float*    C4        = (float*)alloc((size_t)N * 2 * 4);
    ushort_t* Wt1       = (ushort_t*)alloc((size_t)128 * 256 * 2);
    ushort_t* Wt2       = (ushort_t*)alloc((size_t)128 * 128 * 2);
    ushort_t* Wt3       = (ushort_t*)alloc((size_t)64 * 128 * 2);
    (void)ws_size;

    hipMemsetAsync(degi,   0, (size_t)N * 4, stream);
    hipMemsetAsync(cursor, 0, (size_t)N * 4, stream);

    // graph prep
    deg_count_kernel<<<(E + 255) / 256, 256, 0, stream>>>(dstA, degi, E);
    dis_kernel<<<(N + 255) / 256, 256, 0, stream>>>(degi, dis, N);
    const int nb = (N + 1023) >> 10;
    scan_block_kernel<<<nb, 1024, 0, stream>>>(degi, row_start, bsums, N);
    scan_sums_kernel<<<1, 128, 0, stream>>>(bsums, nb);
    scan_add_kernel<<<(N + 256) / 256, 256, 0, stream>>>(row_start, bsums, N, nb);
    scatter_kernel<<<(E + 255) / 256, 256, 0, stream>>>(srcA, dstA, dis, row_start,
                                                        cursor, csr_src, csr_norm, E);

    // dtype conversions
    cast_bf16_kernel<<<(int)(((size_t)N * 64 + 255) / 256), 256, 0, stream>>>(x, xb, (size_t)N * 64);
    wt_kernel<<<(256 * 128 + 255) / 256, 256, 0, stream>>>(W1, Wt1, 256, 128, 256, 128);
    wt_kernel<<<(128 * 128 + 255) / 256, 256, 0, stream>>>(W2, Wt2, 128, 100, 128, 128);
    wt_kernel<<<(128 * 64 + 255) / 256, 256, 0, stream>>>(W3, Wt3, 100, 32, 128, 64);

    const int gx = (N + 127) / 128;
    const int aggBlocks128 = (N + 3) / 4;    // 4 waves/block, 1 node/wave
    const int aggBlocks32  = (N + 15) / 16;  // 16 nodes/block

    // layer 1: 256 -> 128
    mfma_gemm<<<dim3(gx, 2), 256, 0, stream>>>(xb, Wt1, bufA, N, 256, 256, 256, 128, 128);
    aggregate128_kernel<128><<<aggBlocks128, 256, 0, stream>>>(
        bufA, row_start, csr_src, csr_norm, dis, b1, bufB, N);
    // layer 2: 128 -> 100 (padded to 128 with zeros)
    mfma_gemm<<<dim3(gx, 2), 256, 0, stream>>>(bufB, Wt2, bufA, N, 128, 128, 128, 128, 128);
    aggregate128_kernel<100><<<aggBlocks128, 256, 0, stream>>>(
        bufA, row_start, csr_src, csr_norm, dis, b2, bufB, N);
    // layer 3: 128(pad) -> 32
    mfma_gemm<<<dim3(gx, 1), 256, 0, stream>>>(bufB, Wt3, bufA, N, 128, 128, 128, 32, 32);
    aggregate32_kernel<<<aggBlocks32, 256, 0, stream>>>(
        bufA, row_start, csr_src, csr_norm, dis, b3, bufB, N);
    // layer 4: 32 -> 2, aggregate + softmax
    gemm32x2_kernel<<<(N + 255) / 256, 256, 0, stream>>>(bufB, W4, C4, N);
    aggregate2_softmax_kernel<<<(N + 255) / 256, 256, 0, stream>>>(
        C4, row_start, csr_src, csr_norm, dis, b4, (float*)d_out, N);
}